// Round 18
// baseline (165.363 us; speedup 1.0000x reference)
//
#include <hip/hip_runtime.h>
#include <hip/hip_bf16.h>

#define L    112
#define IMG  224
#define IMGSQ (IMG * IMG)             // 50176
#define KS   7
#define CIN  3
#define COUT 64
#define BATCH 32
#define PAD  12
#define NPOS (BATCH * L * L)          // 401408
#define PLANE (L * L)                 // 12544
#define NTOT (NPOS * COUT)            // 25690112
#define EPS  1e-5f
#define KPAD 160
#define W    16                       // j-window width (r6-r17 VERIFIED geometry)
#define NJT  (L / W)                  // 7 windows
#define NB   (NJT * BATCH)            // 224 conv blocks (<= 256 CUs, 1 blk/CU)
#define MAXBAND 80                    // r6-r17 verified bound for W=16
#define BANDPX (MAXBAND * IMG)        // 17920 px per channel
#define LDSPX (CIN * BANDPX)          // 53760
#define PADSLOT LDSPX                 // sentinel slot, holds bf16(0.5)
#define TILE_U16 (5 * 64 * 8)         // 2560 u16 per tile in offset table
#define NTBL (L * NJT * TILE_U16)     // 2007040 u16 (4.01 MB)
#define NLOC (PLANE * KS)             // 87808 locs_i elements
#define CONVTH 512                    // 8 waves, 2/SIMD (no-spill regime)

typedef short bf16x8 __attribute__((ext_vector_type(8)));
typedef float f32x4  __attribute__((ext_vector_type(4)));
typedef unsigned short ushort8 __attribute__((ext_vector_type(8)));

__device__ __forceinline__ short f2bf(float v) {
    __hip_bfloat16 h = __float2bfloat16(v);   // RNE
    return *reinterpret_cast<short*>(&h);
}

__device__ __forceinline__ float bf2f(unsigned short u) {
    return __uint_as_float((unsigned)u << 16);
}

// hw slot -> logical k permutation (must match between weights and table).
__device__ __forceinline__ int hw_to_klog(int hw) {
    const int ks  = hw >> 5;
    const int r32 = hw & 31;
    const int kbi = r32 >> 3;
    const int e   = r32 & 7;
    return ks * 32 + e * 4 + kbi;
}

// row-rotated LDS column (verified r8/r11: conflicts 12.2M -> 2.6M).
__device__ __forceinline__ int swz_col(int col, int ldsrow) {
    int c2 = col + ((ldsrow & 15) << 2);
    return (c2 >= IMG) ? c2 - IMG : c2;
}

// ---------------------------------------------------------------------------
// Prep A: Wt[o][hw] bf16; k_log = c*49 + q*7 + p -> w[o][c][p][q].
// ---------------------------------------------------------------------------
__global__ __launch_bounds__(256) void prep_weights(
    const float* __restrict__ w, unsigned short* __restrict__ wt)
{
    const int idx = blockIdx.x * 256 + threadIdx.x;   // < COUT*KPAD
    const int o  = idx / KPAD;
    const int hw = idx - o * KPAD;
    const int k  = hw_to_klog(hw);
    float v = 0.f;
    if (k < CIN * KS * KS) {
        const int c = (k >= 98) ? 2 : (k >= 49 ? 1 : 0);
        const int r = k - c * 49;
        const int q = (r * 37) >> 8;          // floor(r/7) for r<49
        const int p = r - q * 7;
        v = w[o * (CIN * KS * KS) + c * (KS * KS) + p * KS + q];
    }
    wt[idx] = (unsigned short)f2bf(v);
}

// ---------------------------------------------------------------------------
// Prep B: per-window row min/max via LDS + global atomics.
// ---------------------------------------------------------------------------
__global__ __launch_bounds__(256) void prep_minmax(
    const int* __restrict__ locs_i, int* __restrict__ row_lo,
    int* __restrict__ row_hi)
{
    __shared__ int lmn[NJT], lmx[NJT];
    if (threadIdx.x < NJT) { lmn[threadIdx.x] = 1 << 30; lmx[threadIdx.x] = -(1 << 30); }
    __syncthreads();
    const int idx = blockIdx.x * 256 + threadIdx.x;
    if (idx < NLOC) {
        const int ij = idx / KS;
        const int jt = (ij % L) >> 4;
        const int v  = locs_i[idx] - PAD;
        atomicMin(&lmn[jt], v);
        atomicMax(&lmx[jt], v);
    }
    __syncthreads();
    if (threadIdx.x < NJT) {
        if (lmn[threadIdx.x] < (1 << 30))  atomicMin(&row_lo[threadIdx.x], lmn[threadIdx.x]);
        if (lmx[threadIdx.x] > -(1 << 30)) atomicMax(&row_hi[threadIdx.x], lmx[threadIdx.x]);
    }
}

// ---------------------------------------------------------------------------
// Prep C: LDS-offset table, conv-load-order layout, swizzled columns.
// ---------------------------------------------------------------------------
__global__ __launch_bounds__(256) void prep_ldsoff(
    const int* __restrict__ locs_i, const int* __restrict__ locs_j,
    const int* __restrict__ row_lo, unsigned short* __restrict__ tbl)
{
    const int F = blockIdx.x * 256 + threadIdx.x;
    if (F >= NTBL) return;
    const int tile = F / TILE_U16;
    const int r0   = F - tile * TILE_U16;
    const int ks   = r0 >> 9;
    const int r1   = r0 & 511;
    const int lane = r1 >> 3;
    const int e    = r1 & 7;
    const int jt  = tile / L;
    const int i   = tile - jt * L;
    const int col = lane & 15;
    const int kb  = (lane >> 4) * 8;
    const int hw  = ks * 32 + kb + e;
    const int k   = hw_to_klog(hw);
    const int ij  = i * L + jt * W + col;
    const int lo  = max(row_lo[jt], 0);

    unsigned short off = PADSLOT;
    if (k < CIN * KS * KS) {
        const int c = (k >= 98) ? 2 : (k >= 49 ? 1 : 0);
        const int r = k - c * 49;
        const int q = (r * 37) >> 8;
        const int p = r - q * 7;
        const int row  = locs_i[ij * KS + q] - PAD;
        const int colj = locs_j[ij * KS + p] - PAD;
        if ((unsigned)row < (unsigned)IMG && (unsigned)colj < (unsigned)IMG) {
            const int lr = row - lo;
            off = (unsigned short)(c * BANDPX + lr * IMG + swz_col(colj, lr));
        }
    }
    tbl[F] = off;
}

// ---------------------------------------------------------------------------
// FUSED conv + BN-stats + norm + ReLU. 224 blocks, 1/CU (LDS 108KB) -> all
// co-resident; device-scope spin barrier between stats and normalize.
// Conv body is byte-identical to r17 (pair-unrolled, quad staging).
// After barrier each block normalizes ITS OWN slab (L2-warm, no cross-XCD
// data reads; only the 128 atomically-summed stats cross blocks).
// ---------------------------------------------------------------------------
__global__ __launch_bounds__(CONVTH) void foveal_conv_norm(
    const float* __restrict__ x, const unsigned short* __restrict__ wt,
    const unsigned short* __restrict__ tbl,
    const int* __restrict__ row_lo, const int* __restrict__ row_hi,
    const float* __restrict__ gamma, const float* __restrict__ beta,
    unsigned short* __restrict__ cbf, float* __restrict__ out,
    float* __restrict__ gstats, int* __restrict__ ctr)
{
    __shared__ unsigned short sband[LDSPX + 8];
    __shared__ float ps[2 * COUT];

    const int tid  = threadIdx.x;
    const int lane = tid & 63;
    const int wv   = tid >> 6;                // 0..7

    const int logical = (blockIdx.x & 7) * (NB / 8) + (blockIdx.x >> 3);
    const int jt = logical >> 5;              // 0..6
    const int b  = logical & 31;

    const int lo = max(row_lo[jt], 0);
    int nr = min(row_hi[jt], IMG - 1) - lo + 1;
    nr = min(nr, MAXBAND);

    if (tid < 2 * COUT) ps[tid] = 0.f;
    if (tid == 0) sband[PADSLOT] = 0x3F00;    // bf16(0.5)

    // ---- stage band: quad-vectorized (r17)
    const float* xb = x + (size_t)b * (CIN * IMGSQ) + lo * IMG;
    const int n16 = nr * (IMG / 16);
#pragma unroll
    for (int c = 0; c < CIN; ++c) {
        const float4* src = reinterpret_cast<const float4*>(xb + c * IMGSQ);
        for (int t = tid; t < n16; t += CONVTH) {
            const int r  = t / (IMG / 16);
            const int cq = (t - r * (IMG / 16)) * 16;
            const float4 v0 = src[t * 4 + 0];
            const float4 v1 = src[t * 4 + 1];
            const float4 v2 = src[t * 4 + 2];
            const float4 v3 = src[t * 4 + 3];
            const int base = c * BANDPX + r * IMG;
            uint2 u;
            u.x = ((unsigned)(unsigned short)f2bf(v0.y) << 16) | (unsigned short)f2bf(v0.x);
            u.y = ((unsigned)(unsigned short)f2bf(v0.w) << 16) | (unsigned short)f2bf(v0.z);
            *reinterpret_cast<uint2*>(&sband[base + swz_col(cq + 0, r)]) = u;
            u.x = ((unsigned)(unsigned short)f2bf(v1.y) << 16) | (unsigned short)f2bf(v1.x);
            u.y = ((unsigned)(unsigned short)f2bf(v1.w) << 16) | (unsigned short)f2bf(v1.z);
            *reinterpret_cast<uint2*>(&sband[base + swz_col(cq + 4, r)]) = u;
            u.x = ((unsigned)(unsigned short)f2bf(v2.y) << 16) | (unsigned short)f2bf(v2.x);
            u.y = ((unsigned)(unsigned short)f2bf(v2.w) << 16) | (unsigned short)f2bf(v2.z);
            *reinterpret_cast<uint2*>(&sband[base + swz_col(cq + 8, r)]) = u;
            u.x = ((unsigned)(unsigned short)f2bf(v3.y) << 16) | (unsigned short)f2bf(v3.x);
            u.y = ((unsigned)(unsigned short)f2bf(v3.w) << 16) | (unsigned short)f2bf(v3.z);
            *reinterpret_cast<uint2*>(&sband[base + swz_col(cq + 12, r)]) = u;
        }
    }
    __syncthreads();

    const int col = lane & 15;
    const int kb  = (lane >> 4) * 8;
    const int g   = lane >> 4;

    bf16x8 afrag[4][5];
#pragma unroll
    for (int ct = 0; ct < 4; ++ct)
#pragma unroll
        for (int ks = 0; ks < 5; ++ks)
            afrag[ct][ks] = *reinterpret_cast<const bf16x8*>(
                wt + (ct * 16 + col) * KPAD + ks * 32 + kb);

    float ssum[4][4], sqsum[4][4];
#pragma unroll
    for (int ct = 0; ct < 4; ++ct)
#pragma unroll
        for (int r = 0; r < 4; ++r) { ssum[ct][r] = 0.f; sqsum[ct][r] = 0.f; }

    // ---- 7 tile-pairs per wave (r17 pair-unrolled body)
    for (int pp = 0; pp < 7; ++pp) {
        const int iA = wv + 16 * pp;
        const int iB = iA + 8;

        const unsigned short* opA = tbl + (size_t)(jt * L + iA) * TILE_U16 + lane * 8;
        const unsigned short* opB = tbl + (size_t)(jt * L + iB) * TILE_U16 + lane * 8;
        ushort8 ovA[5], ovB[5];
#pragma unroll
        for (int ks = 0; ks < 5; ++ks)
            ovA[ks] = *reinterpret_cast<const ushort8*>(opA + ks * 512);
#pragma unroll
        for (int ks = 0; ks < 5; ++ks)
            ovB[ks] = *reinterpret_cast<const ushort8*>(opB + ks * 512);

        bf16x8 bfA[5], bfB[5];
#pragma unroll
        for (int ks = 0; ks < 5; ++ks)
#pragma unroll
            for (int e = 0; e < 8; ++e)
                bfA[ks][e] = (short)sband[ovA[ks][e]];
#pragma unroll
        for (int ks = 0; ks < 5; ++ks)
#pragma unroll
            for (int e = 0; e < 8; ++e)
                bfB[ks][e] = (short)sband[ovB[ks][e]];

        f32x4 accA[4], accB[4];
#pragma unroll
        for (int ct = 0; ct < 4; ++ct) {
            accA[ct] = (f32x4){0.f, 0.f, 0.f, 0.f};
            accB[ct] = (f32x4){0.f, 0.f, 0.f, 0.f};
        }

#pragma unroll
        for (int ks = 0; ks < 5; ++ks)
#pragma unroll
            for (int ct = 0; ct < 4; ++ct)
                accA[ct] = __builtin_amdgcn_mfma_f32_16x16x32_bf16(
                    afrag[ct][ks], bfA[ks], accA[ct], 0, 0, 0);

        const size_t obaseA = (size_t)b * COUT * PLANE + iA * L + jt * W + col;
#pragma unroll
        for (int ct = 0; ct < 4; ++ct) {
#pragma unroll
            for (int r = 0; r < 4; ++r) {
                const float v = accA[ct][r];
                cbf[obaseA + (size_t)(ct * 16 + g * 4 + r) * PLANE] =
                    (unsigned short)f2bf(v);
                ssum[ct][r]  += v;
                sqsum[ct][r] += v * v;
            }
        }

#pragma unroll
        for (int ks = 0; ks < 5; ++ks)
#pragma unroll
            for (int ct = 0; ct < 4; ++ct)
                accB[ct] = __builtin_amdgcn_mfma_f32_16x16x32_bf16(
                    afrag[ct][ks], bfB[ks], accB[ct], 0, 0, 0);

        const size_t obaseB = (size_t)b * COUT * PLANE + iB * L + jt * W + col;
#pragma unroll
        for (int ct = 0; ct < 4; ++ct) {
#pragma unroll
            for (int r = 0; r < 4; ++r) {
                const float v = accB[ct][r];
                cbf[obaseB + (size_t)(ct * 16 + g * 4 + r) * PLANE] =
                    (unsigned short)f2bf(v);
                ssum[ct][r]  += v;
                sqsum[ct][r] += v * v;
            }
        }
    }

    // ---- stats: 16-lane reduce -> LDS -> one global atomicAdd per channel
#pragma unroll
    for (int ct = 0; ct < 4; ++ct)
#pragma unroll
        for (int r = 0; r < 4; ++r) {
#pragma unroll
            for (int m = 1; m < 16; m <<= 1) {
                ssum[ct][r]  += __shfl_xor(ssum[ct][r],  m);
                sqsum[ct][r] += __shfl_xor(sqsum[ct][r], m);
            }
        }
    if (col == 0) {
#pragma unroll
        for (int ct = 0; ct < 4; ++ct)
#pragma unroll
            for (int r = 0; r < 4; ++r) {
                const int ch = ct * 16 + g * 4 + r;
                atomicAdd(&ps[ch], ssum[ct][r]);
                atomicAdd(&ps[COUT + ch], sqsum[ct][r]);
            }
    }
    __syncthreads();
    if (tid < 2 * COUT) atomicAdd(&gstats[tid], ps[tid]);   // device scope

    // ---- grid barrier (224 co-resident blocks; release/acquire on ctr)
    __threadfence();
    __syncthreads();
    if (tid == 0) {
        __hip_atomic_fetch_add(ctr, 1, __ATOMIC_RELEASE, __HIP_MEMORY_SCOPE_AGENT);
        while (__hip_atomic_load(ctr, __ATOMIC_ACQUIRE, __HIP_MEMORY_SCOPE_AGENT) < NB)
            __builtin_amdgcn_s_sleep(8);
    }
    __syncthreads();

    // ---- fold stats -> per-channel scale/shift in LDS
    if (tid < COUT) {
        const float n = (float)NPOS;
        const float s  = gstats[tid];
        const float sq = gstats[COUT + tid];
        const float mean = s / n;
        float var = sq / n - mean * mean;
        var = fmaxf(var, 0.f);
        const float sc = gamma[tid] * rsqrtf(var + EPS);
        ps[tid] = sc;
        ps[COUT + tid] = beta[tid] - mean * sc;
    }
    __syncthreads();

    // ---- normalize own slab (L2-warm): 64ch x 112i x 2 halves of 8 px
    const size_t slab = (size_t)b * COUT * PLANE + jt * W;
    for (int m = tid; m < COUT * L * 2; m += CONVTH) {
        const int ch = m / (L * 2);
        const int rr = m - ch * (L * 2);
        const int i  = rr >> 1;
        const int hf = rr & 1;
        const size_t base = slab + (size_t)ch * PLANE + (size_t)i * L + hf * 8;
        const ushort8 u = *reinterpret_cast<const ushort8*>(cbf + base);
        const float sc = ps[ch];
        const float sh = ps[COUT + ch];
        float4 a, c;
        a.x = fmaxf(fmaf(bf2f(u[0]), sc, sh), 0.f);
        a.y = fmaxf(fmaf(bf2f(u[1]), sc, sh), 0.f);
        a.z = fmaxf(fmaf(bf2f(u[2]), sc, sh), 0.f);
        a.w = fmaxf(fmaf(bf2f(u[3]), sc, sh), 0.f);
        c.x = fmaxf(fmaf(bf2f(u[4]), sc, sh), 0.f);
        c.y = fmaxf(fmaf(bf2f(u[5]), sc, sh), 0.f);
        c.z = fmaxf(fmaf(bf2f(u[6]), sc, sh), 0.f);
        c.w = fmaxf(fmaf(bf2f(u[7]), sc, sh), 0.f);
        *reinterpret_cast<float4*>(out + base)     = a;
        *reinterpret_cast<float4*>(out + base + 4) = c;
    }
}

// ---------------------------------------------------------------------------
extern "C" void kernel_launch(void* const* d_in, const int* in_sizes, int n_in,
                              void* d_out, int out_size, void* d_ws, size_t ws_size,
                              hipStream_t stream)
{
    const float* x      = (const float*)d_in[0];
    const float* conv_w = (const float*)d_in[1];
    const float* gamma  = (const float*)d_in[2];
    const float* beta   = (const float*)d_in[3];
    const int*   locs_i = (const int*)d_in[4];
    const int*   locs_j = (const int*)d_in[5];
    float* out = (float*)d_out;

    float* gstats = (float*)d_ws;                                   // 512 B
    int* row_lo   = (int*)((char*)d_ws + 512);                      // 28 B
    int* row_hi   = (int*)((char*)d_ws + 768);                      // 28 B
    int* ctr      = (int*)((char*)d_ws + 896);                      // 4 B
    unsigned short* wt = (unsigned short*)((char*)d_ws + 2048);     // 20480 B
    unsigned short* tbl =
        (unsigned short*)((char*)d_ws + (1u << 20));                // 4.01 MB
    unsigned short* cbf =
        (unsigned short*)((char*)d_ws + (6u << 20));                // 51.4 MB

    // zero stats + barrier counter, then init min/max
    hipMemsetAsync(d_ws, 0, 1024, stream);
    hipMemsetAsync(row_lo, 0x7F, NJT * sizeof(int), stream);        // +big
    hipMemsetAsync(row_hi, 0x80, NJT * sizeof(int), stream);        // -big

    prep_weights<<<(COUT * KPAD) / 256, 256, 0, stream>>>(conv_w, wt);
    prep_minmax<<<(NLOC + 255) / 256, 256, 0, stream>>>(locs_i, row_lo, row_hi);
    prep_ldsoff<<<(NTBL + 255) / 256, 256, 0, stream>>>(
        locs_i, locs_j, row_lo, tbl);
    foveal_conv_norm<<<NB, CONVTH, 0, stream>>>(
        x, wt, tbl, row_lo, row_hi, gamma, beta, cbf, out, gstats, ctr);
}

// Round 19
// 89.307 us; speedup vs baseline: 1.8516x; 1.8516x over previous
//
#include <hip/hip_runtime.h>
#include <hip/hip_bf16.h>

#define L    112
#define IMG  224
#define IMGSQ (IMG * IMG)             // 50176
#define KS   7
#define CIN  3
#define COUT 64
#define BATCH 32
#define PAD  12
#define NPOS (BATCH * L * L)          // 401408
#define PLANE (L * L)                 // 12544
#define NTOT (NPOS * COUT)            // 25690112
#define EPS  1e-5f
#define KPAD 160
#define W    16                       // j-window width (r6-r17 VERIFIED geometry)
#define NJT  (L / W)                  // 7 windows
#define NB   (NJT * BATCH)            // 224 conv blocks
#define MAXBAND 80                    // r6-r17 verified bound for W=16
#define BANDPX (MAXBAND * IMG)        // 17920 px per channel
#define LDSPX (CIN * BANDPX)          // 53760
#define PADSLOT LDSPX                 // sentinel slot, holds bf16(0.5)
#define TILE_U16 (5 * 64 * 8)         // 2560 u16 per tile in offset table
#define NTBL (L * NJT * TILE_U16)     // 2007040 u16 (4.01 MB)
#define NLOC (PLANE * KS)             // 87808 locs_i elements
#define CONVTH 512                    // 8 waves, 2/SIMD (no-spill regime)
#define WBLK 40                       // prep blocks doing weights
#define MMBLK ((NLOC + 255) / 256)    // prep blocks doing minmax (343)

typedef short bf16x8 __attribute__((ext_vector_type(8)));
typedef float f32x4  __attribute__((ext_vector_type(4)));
typedef unsigned short ushort8 __attribute__((ext_vector_type(8)));

__device__ __forceinline__ short f2bf(float v) {
    __hip_bfloat16 h = __float2bfloat16(v);   // RNE
    return *reinterpret_cast<short*>(&h);
}

// hw slot -> logical k permutation (must match between weights and table).
__device__ __forceinline__ int hw_to_klog(int hw) {
    const int ks  = hw >> 5;
    const int r32 = hw & 31;
    const int kbi = r32 >> 3;
    const int e   = r32 & 7;
    return ks * 32 + e * 4 + kbi;
}

// row-rotated LDS column (verified r8/r11: conflicts 12.2M -> 2.6M).
__device__ __forceinline__ int swz_col(int col, int ldsrow) {
    int c2 = col + ((ldsrow & 15) << 2);
    return (c2 >= IMG) ? c2 - IMG : c2;
}

// ---------------------------------------------------------------------------
// Prep A+B merged: blocks [0,WBLK) build Wt; blocks [WBLK, WBLK+MMBLK) do
// per-window row min/max (LDS + global atomics).
// ---------------------------------------------------------------------------
__global__ __launch_bounds__(256) void prep_wt_minmax(
    const float* __restrict__ w, unsigned short* __restrict__ wt,
    const int* __restrict__ locs_i, int* __restrict__ row_lo,
    int* __restrict__ row_hi)
{
    if (blockIdx.x < WBLK) {
        const int idx = blockIdx.x * 256 + threadIdx.x;   // < COUT*KPAD
        const int o  = idx / KPAD;
        const int hw = idx - o * KPAD;
        const int k  = hw_to_klog(hw);
        float v = 0.f;
        if (k < CIN * KS * KS) {
            const int c = (k >= 98) ? 2 : (k >= 49 ? 1 : 0);
            const int r = k - c * 49;
            const int q = (r * 37) >> 8;      // floor(r/7) for r<49
            const int p = r - q * 7;
            v = w[o * (CIN * KS * KS) + c * (KS * KS) + p * KS + q];
        }
        wt[idx] = (unsigned short)f2bf(v);
        return;
    }
    __shared__ int lmn[NJT], lmx[NJT];
    if (threadIdx.x < NJT) { lmn[threadIdx.x] = 1 << 30; lmx[threadIdx.x] = -(1 << 30); }
    __syncthreads();
    const int idx = (blockIdx.x - WBLK) * 256 + threadIdx.x;
    if (idx < NLOC) {
        const int ij = idx / KS;
        const int jt = (ij % L) >> 4;
        const int v  = locs_i[idx] - PAD;
        atomicMin(&lmn[jt], v);
        atomicMax(&lmx[jt], v);
    }
    __syncthreads();
    if (threadIdx.x < NJT) {
        if (lmn[threadIdx.x] < (1 << 30))  atomicMin(&row_lo[threadIdx.x], lmn[threadIdx.x]);
        if (lmx[threadIdx.x] > -(1 << 30)) atomicMax(&row_hi[threadIdx.x], lmx[threadIdx.x]);
    }
}

// ---------------------------------------------------------------------------
// Prep C: LDS-offset table, conv-load-order layout, swizzled columns:
//   tbl[tile][ks][lane][e], tile = jt*112 + i, lane = (kbgrp<<4)|col.
// ---------------------------------------------------------------------------
__global__ __launch_bounds__(256) void prep_ldsoff(
    const int* __restrict__ locs_i, const int* __restrict__ locs_j,
    const int* __restrict__ row_lo, unsigned short* __restrict__ tbl)
{
    const int F = blockIdx.x * 256 + threadIdx.x;
    if (F >= NTBL) return;
    const int tile = F / TILE_U16;
    const int r0   = F - tile * TILE_U16;
    const int ks   = r0 >> 9;
    const int r1   = r0 & 511;
    const int lane = r1 >> 3;
    const int e    = r1 & 7;
    const int jt  = tile / L;
    const int i   = tile - jt * L;
    const int col = lane & 15;
    const int kb  = (lane >> 4) * 8;
    const int hw  = ks * 32 + kb + e;
    const int k   = hw_to_klog(hw);
    const int ij  = i * L + jt * W + col;
    const int lo  = max(row_lo[jt], 0);

    unsigned short off = PADSLOT;
    if (k < CIN * KS * KS) {
        const int c = (k >= 98) ? 2 : (k >= 49 ? 1 : 0);
        const int r = k - c * 49;
        const int q = (r * 37) >> 8;
        const int p = r - q * 7;
        const int row  = locs_i[ij * KS + q] - PAD;
        const int colj = locs_j[ij * KS + p] - PAD;
        if ((unsigned)row < (unsigned)IMG && (unsigned)colj < (unsigned)IMG) {
            const int lr = row - lo;
            off = (unsigned short)(c * BANDPX + lr * IMG + swz_col(colj, lr));
        }
    }
    tbl[F] = off;
}

// ---------------------------------------------------------------------------
// Conv (r17 structure, verified 92.7us total): quad-vectorized staging,
// pair-unrolled tile loop with disjoint register sets. NEW: s_setprio(1)
// around the MFMA clusters (waves are barrier-free post-staging and drift
// into different phases -> the T5-favorable regime).
// ---------------------------------------------------------------------------
template<bool BF16OUT>
__global__ __launch_bounds__(CONVTH) void foveal_conv_mfma(
    const float* __restrict__ x, const unsigned short* __restrict__ wt,
    const unsigned short* __restrict__ tbl,
    const int* __restrict__ row_lo, const int* __restrict__ row_hi,
    float* __restrict__ out_f32, unsigned short* __restrict__ out_bf16,
    float* __restrict__ partial)
{
    __shared__ unsigned short sband[LDSPX + 8];
    __shared__ float ps[2 * COUT];

    const int tid  = threadIdx.x;
    const int lane = tid & 63;
    const int wv   = tid >> 6;                // 0..7

    // chunked XCD swizzle: 28 consecutive logical blocks per XCD
    const int logical = (blockIdx.x & 7) * (NB / 8) + (blockIdx.x >> 3);
    const int jt = logical >> 5;              // 0..6
    const int b  = logical & 31;

    const int lo = max(row_lo[jt], 0);
    int nr = min(row_hi[jt], IMG - 1) - lo + 1;
    nr = min(nr, MAXBAND);

    if (tid < 2 * COUT) ps[tid] = 0.f;
    if (tid == 0) sband[PADSLOT] = 0x3F00;    // bf16(0.5)

    // ---- stage band: quad-vectorized (4 independent float4 loads/iter)
    const float* xb = x + (size_t)b * (CIN * IMGSQ) + lo * IMG;
    const int n16 = nr * (IMG / 16);
#pragma unroll
    for (int c = 0; c < CIN; ++c) {
        const float4* src = reinterpret_cast<const float4*>(xb + c * IMGSQ);
        for (int t = tid; t < n16; t += CONVTH) {
            const int r  = t / (IMG / 16);
            const int cq = (t - r * (IMG / 16)) * 16;
            const float4 v0 = src[t * 4 + 0];
            const float4 v1 = src[t * 4 + 1];
            const float4 v2 = src[t * 4 + 2];
            const float4 v3 = src[t * 4 + 3];
            const int base = c * BANDPX + r * IMG;
            uint2 u;
            u.x = ((unsigned)(unsigned short)f2bf(v0.y) << 16) | (unsigned short)f2bf(v0.x);
            u.y = ((unsigned)(unsigned short)f2bf(v0.w) << 16) | (unsigned short)f2bf(v0.z);
            *reinterpret_cast<uint2*>(&sband[base + swz_col(cq + 0, r)]) = u;
            u.x = ((unsigned)(unsigned short)f2bf(v1.y) << 16) | (unsigned short)f2bf(v1.x);
            u.y = ((unsigned)(unsigned short)f2bf(v1.w) << 16) | (unsigned short)f2bf(v1.z);
            *reinterpret_cast<uint2*>(&sband[base + swz_col(cq + 4, r)]) = u;
            u.x = ((unsigned)(unsigned short)f2bf(v2.y) << 16) | (unsigned short)f2bf(v2.x);
            u.y = ((unsigned)(unsigned short)f2bf(v2.w) << 16) | (unsigned short)f2bf(v2.z);
            *reinterpret_cast<uint2*>(&sband[base + swz_col(cq + 8, r)]) = u;
            u.x = ((unsigned)(unsigned short)f2bf(v3.y) << 16) | (unsigned short)f2bf(v3.x);
            u.y = ((unsigned)(unsigned short)f2bf(v3.w) << 16) | (unsigned short)f2bf(v3.z);
            *reinterpret_cast<uint2*>(&sband[base + swz_col(cq + 12, r)]) = u;
        }
    }
    __syncthreads();

    const int col = lane & 15;
    const int kb  = (lane >> 4) * 8;
    const int g   = lane >> 4;

    // ---- weights: lane-dependent only -> hoist once per wave (L1-hot)
    bf16x8 afrag[4][5];
#pragma unroll
    for (int ct = 0; ct < 4; ++ct)
#pragma unroll
        for (int ks = 0; ks < 5; ++ks)
            afrag[ct][ks] = *reinterpret_cast<const bf16x8*>(
                wt + (ct * 16 + col) * KPAD + ks * 32 + kb);

    // ---- per-lane BN partial accumulators (ch = ct*16 + g*4 + r)
    float ssum[4][4], sqsum[4][4];
#pragma unroll
    for (int ct = 0; ct < 4; ++ct)
#pragma unroll
        for (int r = 0; r < 4; ++r) { ssum[ct][r] = 0.f; sqsum[ct][r] = 0.f; }

    // ---- 7 tile-pairs per wave: iA = wv+16pp, iB = iA+8
    for (int pp = 0; pp < 7; ++pp) {
        const int iA = wv + 16 * pp;
        const int iB = iA + 8;

        const unsigned short* opA = tbl + (size_t)(jt * L + iA) * TILE_U16 + lane * 8;
        const unsigned short* opB = tbl + (size_t)(jt * L + iB) * TILE_U16 + lane * 8;
        ushort8 ovA[5], ovB[5];
#pragma unroll
        for (int ks = 0; ks < 5; ++ks)
            ovA[ks] = *reinterpret_cast<const ushort8*>(opA + ks * 512);
#pragma unroll
        for (int ks = 0; ks < 5; ++ks)
            ovB[ks] = *reinterpret_cast<const ushort8*>(opB + ks * 512);

        // 80 independent LDS gathers into disjoint register sets
        bf16x8 bfA[5], bfB[5];
#pragma unroll
        for (int ks = 0; ks < 5; ++ks)
#pragma unroll
            for (int e = 0; e < 8; ++e)
                bfA[ks][e] = (short)sband[ovA[ks][e]];
#pragma unroll
        for (int ks = 0; ks < 5; ++ks)
#pragma unroll
            for (int e = 0; e < 8; ++e)
                bfB[ks][e] = (short)sband[ovB[ks][e]];

        f32x4 accA[4], accB[4];
#pragma unroll
        for (int ct = 0; ct < 4; ++ct) {
            accA[ct] = (f32x4){0.f, 0.f, 0.f, 0.f};
            accB[ct] = (f32x4){0.f, 0.f, 0.f, 0.f};
        }

        __builtin_amdgcn_s_setprio(1);
#pragma unroll
        for (int ks = 0; ks < 5; ++ks)
#pragma unroll
            for (int ct = 0; ct < 4; ++ct)
                accA[ct] = __builtin_amdgcn_mfma_f32_16x16x32_bf16(
                    afrag[ct][ks], bfA[ks], accA[ct], 0, 0, 0);
        __builtin_amdgcn_s_setprio(0);

        const size_t obaseA = (size_t)b * COUT * PLANE + iA * L + jt * W + col;
#pragma unroll
        for (int ct = 0; ct < 4; ++ct) {
#pragma unroll
            for (int r = 0; r < 4; ++r) {
                const float v = accA[ct][r];
                const size_t oidx = obaseA + (size_t)(ct * 16 + g * 4 + r) * PLANE;
                if (BF16OUT) out_bf16[oidx] = (unsigned short)f2bf(v);
                else         out_f32[oidx] = v;
                ssum[ct][r]  += v;
                sqsum[ct][r] += v * v;
            }
        }

        __builtin_amdgcn_s_setprio(1);
#pragma unroll
        for (int ks = 0; ks < 5; ++ks)
#pragma unroll
            for (int ct = 0; ct < 4; ++ct)
                accB[ct] = __builtin_amdgcn_mfma_f32_16x16x32_bf16(
                    afrag[ct][ks], bfB[ks], accB[ct], 0, 0, 0);
        __builtin_amdgcn_s_setprio(0);

        const size_t obaseB = (size_t)b * COUT * PLANE + iB * L + jt * W + col;
#pragma unroll
        for (int ct = 0; ct < 4; ++ct) {
#pragma unroll
            for (int r = 0; r < 4; ++r) {
                const float v = accB[ct][r];
                const size_t oidx = obaseB + (size_t)(ct * 16 + g * 4 + r) * PLANE;
                if (BF16OUT) out_bf16[oidx] = (unsigned short)f2bf(v);
                else         out_f32[oidx] = v;
                ssum[ct][r]  += v;
                sqsum[ct][r] += v * v;
            }
        }
    }

    // ---- fold per-lane stats: reduce over the 16 cols of each group
#pragma unroll
    for (int ct = 0; ct < 4; ++ct)
#pragma unroll
        for (int r = 0; r < 4; ++r) {
#pragma unroll
            for (int m = 1; m < 16; m <<= 1) {
                ssum[ct][r]  += __shfl_xor(ssum[ct][r],  m);
                sqsum[ct][r] += __shfl_xor(sqsum[ct][r], m);
            }
        }
    if (col == 0) {
#pragma unroll
        for (int ct = 0; ct < 4; ++ct)
#pragma unroll
            for (int r = 0; r < 4; ++r) {
                const int ch = ct * 16 + g * 4 + r;
                atomicAdd(&ps[ch], ssum[ct][r]);
                atomicAdd(&ps[COUT + ch], sqsum[ct][r]);
            }
    }
    __syncthreads();
    if (tid < 2 * COUT) partial[(size_t)blockIdx.x * (2 * COUT) + tid] = ps[tid];
}

// ---------------------------------------------------------------------------
// Fold: per-channel scale/shift from block partials.
// ---------------------------------------------------------------------------
__global__ __launch_bounds__(256) void fold_stats(
    const float* __restrict__ partial, const float* __restrict__ gamma,
    const float* __restrict__ beta, float* __restrict__ wsf)
{
    const int o = blockIdx.x;                 // 64 blocks
    float s = 0.f, sq = 0.f;
    for (int t = threadIdx.x; t < NB; t += 256) {
        s  += partial[(size_t)t * (2 * COUT) + o];
        sq += partial[(size_t)t * (2 * COUT) + COUT + o];
    }
#pragma unroll
    for (int m = 1; m < 64; m <<= 1) {
        s  += __shfl_xor(s, m);
        sq += __shfl_xor(sq, m);
    }
    __shared__ float ls[4], lsq[4];
    const int wid = threadIdx.x >> 6;
    if ((threadIdx.x & 63) == 0) { ls[wid] = s; lsq[wid] = sq; }
    __syncthreads();
    if (threadIdx.x == 0) {
        s  = ls[0] + ls[1] + ls[2] + ls[3];
        sq = lsq[0] + lsq[1] + lsq[2] + lsq[3];
        const float n = (float)NPOS;
        const float mean = s / n;
        float var = sq / n - mean * mean;
        var = fmaxf(var, 0.f);
        const float sc = gamma[o] * rsqrtf(var + EPS);
        wsf[o] = sc;
        wsf[COUT + o] = beta[o] - mean * sc;
    }
}

// ---------------------------------------------------------------------------
// Norm + ReLU. bf16 variant: read ushort8 from ws, write 2x float4 to d_out.
// ---------------------------------------------------------------------------
__global__ __launch_bounds__(256) void norm_relu_bf16(
    const ushort8* __restrict__ in, float4* __restrict__ out,
    const float* __restrict__ wsf)
{
    const int idx = blockIdx.x * 256 + threadIdx.x;   // < NTOT/8
    const int o = (idx / (PLANE / 8)) & (COUT - 1);
    const float sc = wsf[o];
    const float sh = wsf[COUT + o];
    const ushort8 u = in[idx];
    float4 a, c;
    a.x = fmaxf(fmaf(__uint_as_float((unsigned)u[0] << 16), sc, sh), 0.f);
    a.y = fmaxf(fmaf(__uint_as_float((unsigned)u[1] << 16), sc, sh), 0.f);
    a.z = fmaxf(fmaf(__uint_as_float((unsigned)u[2] << 16), sc, sh), 0.f);
    a.w = fmaxf(fmaf(__uint_as_float((unsigned)u[3] << 16), sc, sh), 0.f);
    c.x = fmaxf(fmaf(__uint_as_float((unsigned)u[4] << 16), sc, sh), 0.f);
    c.y = fmaxf(fmaf(__uint_as_float((unsigned)u[5] << 16), sc, sh), 0.f);
    c.z = fmaxf(fmaf(__uint_as_float((unsigned)u[6] << 16), sc, sh), 0.f);
    c.w = fmaxf(fmaf(__uint_as_float((unsigned)u[7] << 16), sc, sh), 0.f);
    out[idx * 2]     = a;
    out[idx * 2 + 1] = c;
}

// fp32 in-place fallback
__global__ __launch_bounds__(256) void norm_relu(
    float4* __restrict__ out, const float* __restrict__ wsf)
{
    const int idx = blockIdx.x * 256 + threadIdx.x;   // < NTOT/4
    const int o = (idx / (PLANE / 4)) & (COUT - 1);
    const float sc = wsf[o];
    const float sh = wsf[COUT + o];
    float4 v = out[idx];
    v.x = fmaxf(fmaf(v.x, sc, sh), 0.f);
    v.y = fmaxf(fmaf(v.y, sc, sh), 0.f);
    v.z = fmaxf(fmaf(v.z, sc, sh), 0.f);
    v.w = fmaxf(fmaf(v.w, sc, sh), 0.f);
    out[idx] = v;
}

// ---------------------------------------------------------------------------
extern "C" void kernel_launch(void* const* d_in, const int* in_sizes, int n_in,
                              void* d_out, int out_size, void* d_ws, size_t ws_size,
                              hipStream_t stream)
{
    const float* x      = (const float*)d_in[0];
    const float* conv_w = (const float*)d_in[1];
    const float* gamma  = (const float*)d_in[2];
    const float* beta   = (const float*)d_in[3];
    const int*   locs_i = (const int*)d_in[4];
    const int*   locs_j = (const int*)d_in[5];
    float* out = (float*)d_out;

    float* wsf   = (float*)d_ws;                                    // 512 B
    int* row_lo  = (int*)((char*)d_ws + 512);                       // 28 B
    int* row_hi  = (int*)((char*)d_ws + 768);                       // 28 B
    unsigned short* wt = (unsigned short*)((char*)d_ws + 2048);     // 20480 B
    float* partial = (float*)((char*)d_ws + 32768);                 // 114688 B
    unsigned short* tbl =
        (unsigned short*)((char*)d_ws + (1u << 20));                // 4.01 MB
    unsigned short* cbf =
        (unsigned short*)((char*)d_ws + (6u << 20));                // 51.4 MB

    const bool use_bf16 = ws_size >= (size_t)(6u << 20) + (size_t)NTOT * 2;

    hipMemsetAsync(row_lo, 0x7F, NJT * sizeof(int), stream);        // +big
    hipMemsetAsync(row_hi, 0x80, NJT * sizeof(int), stream);        // -big

    prep_wt_minmax<<<WBLK + MMBLK, 256, 0, stream>>>(
        conv_w, wt, locs_i, row_lo, row_hi);
    prep_ldsoff<<<(NTBL + 255) / 256, 256, 0, stream>>>(
        locs_i, locs_j, row_lo, tbl);
    if (use_bf16) {
        foveal_conv_mfma<true><<<NB, CONVTH, 0, stream>>>(
            x, wt, tbl, row_lo, row_hi, out, cbf, partial);
        fold_stats<<<COUT, 256, 0, stream>>>(partial, gamma, beta, wsf);
        norm_relu_bf16<<<NTOT / 8 / 256, 256, 0, stream>>>(
            (const ushort8*)cbf, (float4*)out, wsf);
    } else {
        foveal_conv_mfma<false><<<NB, CONVTH, 0, stream>>>(
            x, wt, tbl, row_lo, row_hi, out, cbf, partial);
        fold_stats<<<COUT, 256, 0, stream>>>(partial, gamma, beta, wsf);
        norm_relu<<<NTOT / 4 / 256, 256, 0, stream>>>((float4*)out, wsf);
    }
}

// Round 20
// 82.538 us; speedup vs baseline: 2.0035x; 1.0820x over previous
//
#include <hip/hip_runtime.h>
#include <hip/hip_bf16.h>

#define L    112
#define IMG  224
#define IMGSQ (IMG * IMG)             // 50176
#define KS   7
#define CIN  3
#define COUT 64
#define BATCH 32
#define PAD  12
#define NPOS (BATCH * L * L)          // 401408
#define PLANE (L * L)                 // 12544
#define NTOT (NPOS * COUT)            // 25690112
#define EPS  1e-5f
#define KPAD 160
#define W    16                       // j-window width (r6-r19 VERIFIED geometry)
#define NJT  (L / W)                  // 7 windows
#define NB   (NJT * BATCH)            // 224 conv blocks
#define MAXBAND 80                    // r6-r19 verified bound for W=16
#define BANDPX (MAXBAND * IMG)        // 17920 px per channel
#define LDSPX (CIN * BANDPX)          // 53760
#define PADSLOT LDSPX                 // sentinel slot, holds bf16(0.5)
#define TILE_U16 (5 * 64 * 8)         // 2560 u16 per tile in offset table
#define NTBL (L * NJT * TILE_U16)     // 2007040 u16 (4.01 MB)
#define NLOC (PLANE * KS)             // 87808 locs_i elements
#define CONVTH 512                    // 8 waves, 2/SIMD (no-spill regime)
#define WBLK 40                       // prep blocks doing weights
#define MMBLK ((NLOC + 255) / 256)    // prep blocks doing minmax (343)
// packed cbf layout: [b][jt][i][ct][g][col][r], 1024 u16 per (b,jt,i)
#define PBLK 1024

typedef short bf16x8 __attribute__((ext_vector_type(8)));
typedef float f32x4  __attribute__((ext_vector_type(4)));
typedef unsigned short ushort8 __attribute__((ext_vector_type(8)));
typedef unsigned short us4 __attribute__((ext_vector_type(4)));

__device__ __forceinline__ short f2bf(float v) {
    __hip_bfloat16 h = __float2bfloat16(v);   // RNE
    return *reinterpret_cast<short*>(&h);
}

__device__ __forceinline__ float bf2f(unsigned short u) {
    return __uint_as_float((unsigned)u << 16);
}

// hw slot -> logical k permutation (must match between weights and table).
__device__ __forceinline__ int hw_to_klog(int hw) {
    const int ks  = hw >> 5;
    const int r32 = hw & 31;
    const int kbi = r32 >> 3;
    const int e   = r32 & 7;
    return ks * 32 + e * 4 + kbi;
}

// row-rotated LDS column (verified r8/r11: conflicts 12.2M -> 2.6M).
__device__ __forceinline__ int swz_col(int col, int ldsrow) {
    int c2 = col + ((ldsrow & 15) << 2);
    return (c2 >= IMG) ? c2 - IMG : c2;
}

// ---------------------------------------------------------------------------
// Prep A+B merged: blocks [0,WBLK) build Wt; the rest do row min/max.
// ---------------------------------------------------------------------------
__global__ __launch_bounds__(256) void prep_wt_minmax(
    const float* __restrict__ w, unsigned short* __restrict__ wt,
    const int* __restrict__ locs_i, int* __restrict__ row_lo,
    int* __restrict__ row_hi)
{
    if (blockIdx.x < WBLK) {
        const int idx = blockIdx.x * 256 + threadIdx.x;   // < COUT*KPAD
        const int o  = idx / KPAD;
        const int hw = idx - o * KPAD;
        const int k  = hw_to_klog(hw);
        float v = 0.f;
        if (k < CIN * KS * KS) {
            const int c = (k >= 98) ? 2 : (k >= 49 ? 1 : 0);
            const int r = k - c * 49;
            const int q = (r * 37) >> 8;      // floor(r/7) for r<49
            const int p = r - q * 7;
            v = w[o * (CIN * KS * KS) + c * (KS * KS) + p * KS + q];
        }
        wt[idx] = (unsigned short)f2bf(v);
        return;
    }
    __shared__ int lmn[NJT], lmx[NJT];
    if (threadIdx.x < NJT) { lmn[threadIdx.x] = 1 << 30; lmx[threadIdx.x] = -(1 << 30); }
    __syncthreads();
    const int idx = (blockIdx.x - WBLK) * 256 + threadIdx.x;
    if (idx < NLOC) {
        const int ij = idx / KS;
        const int jt = (ij % L) >> 4;
        const int v  = locs_i[idx] - PAD;
        atomicMin(&lmn[jt], v);
        atomicMax(&lmx[jt], v);
    }
    __syncthreads();
    if (threadIdx.x < NJT) {
        if (lmn[threadIdx.x] < (1 << 30))  atomicMin(&row_lo[threadIdx.x], lmn[threadIdx.x]);
        if (lmx[threadIdx.x] > -(1 << 30)) atomicMax(&row_hi[threadIdx.x], lmx[threadIdx.x]);
    }
}

// ---------------------------------------------------------------------------
// Prep C: LDS-offset table, conv-load-order layout, swizzled columns.
// ---------------------------------------------------------------------------
__global__ __launch_bounds__(256) void prep_ldsoff(
    const int* __restrict__ locs_i, const int* __restrict__ locs_j,
    const int* __restrict__ row_lo, unsigned short* __restrict__ tbl)
{
    const int F = blockIdx.x * 256 + threadIdx.x;
    if (F >= NTBL) return;
    const int tile = F / TILE_U16;
    const int r0   = F - tile * TILE_U16;
    const int ks   = r0 >> 9;
    const int r1   = r0 & 511;
    const int lane = r1 >> 3;
    const int e    = r1 & 7;
    const int jt  = tile / L;
    const int i   = tile - jt * L;
    const int col = lane & 15;
    const int kb  = (lane >> 4) * 8;
    const int hw  = ks * 32 + kb + e;
    const int k   = hw_to_klog(hw);
    const int ij  = i * L + jt * W + col;
    const int lo  = max(row_lo[jt], 0);

    unsigned short off = PADSLOT;
    if (k < CIN * KS * KS) {
        const int c = (k >= 98) ? 2 : (k >= 49 ? 1 : 0);
        const int r = k - c * 49;
        const int q = (r * 37) >> 8;
        const int p = r - q * 7;
        const int row  = locs_i[ij * KS + q] - PAD;
        const int colj = locs_j[ij * KS + p] - PAD;
        if ((unsigned)row < (unsigned)IMG && (unsigned)colj < (unsigned)IMG) {
            const int lr = row - lo;
            off = (unsigned short)(c * BANDPX + lr * IMG + swz_col(colj, lr));
        }
    }
    tbl[F] = off;
}

// ---------------------------------------------------------------------------
// Conv (r19 structure): quad staging, pair-unrolled tiles, setprio MFMA.
// NEW: BF16OUT path stores the packed layout [b][jt][i][ct][g][col][r] --
// one ushort4 (8B) per ct, 512B contiguous per wave-store -> 4 store instrs
// per tile instead of 16 scalar PLANE-strided shorts (store pipe ~19% of
// conv cycles, cut ~4x).
// ---------------------------------------------------------------------------
template<bool BF16OUT>
__global__ __launch_bounds__(CONVTH) void foveal_conv_mfma(
    const float* __restrict__ x, const unsigned short* __restrict__ wt,
    const unsigned short* __restrict__ tbl,
    const int* __restrict__ row_lo, const int* __restrict__ row_hi,
    float* __restrict__ out_f32, unsigned short* __restrict__ out_bf16,
    float* __restrict__ partial)
{
    __shared__ unsigned short sband[LDSPX + 8];
    __shared__ float ps[2 * COUT];

    const int tid  = threadIdx.x;
    const int lane = tid & 63;
    const int wv   = tid >> 6;                // 0..7

    // chunked XCD swizzle: 28 consecutive logical blocks per XCD
    const int logical = (blockIdx.x & 7) * (NB / 8) + (blockIdx.x >> 3);
    const int jt = logical >> 5;              // 0..6
    const int b  = logical & 31;

    const int lo = max(row_lo[jt], 0);
    int nr = min(row_hi[jt], IMG - 1) - lo + 1;
    nr = min(nr, MAXBAND);

    if (tid < 2 * COUT) ps[tid] = 0.f;
    if (tid == 0) sband[PADSLOT] = 0x3F00;    // bf16(0.5)

    // ---- stage band: quad-vectorized (4 independent float4 loads/iter)
    const float* xb = x + (size_t)b * (CIN * IMGSQ) + lo * IMG;
    const int n16 = nr * (IMG / 16);
#pragma unroll
    for (int c = 0; c < CIN; ++c) {
        const float4* src = reinterpret_cast<const float4*>(xb + c * IMGSQ);
        for (int t = tid; t < n16; t += CONVTH) {
            const int r  = t / (IMG / 16);
            const int cq = (t - r * (IMG / 16)) * 16;
            const float4 v0 = src[t * 4 + 0];
            const float4 v1 = src[t * 4 + 1];
            const float4 v2 = src[t * 4 + 2];
            const float4 v3 = src[t * 4 + 3];
            const int base = c * BANDPX + r * IMG;
            uint2 u;
            u.x = ((unsigned)(unsigned short)f2bf(v0.y) << 16) | (unsigned short)f2bf(v0.x);
            u.y = ((unsigned)(unsigned short)f2bf(v0.w) << 16) | (unsigned short)f2bf(v0.z);
            *reinterpret_cast<uint2*>(&sband[base + swz_col(cq + 0, r)]) = u;
            u.x = ((unsigned)(unsigned short)f2bf(v1.y) << 16) | (unsigned short)f2bf(v1.x);
            u.y = ((unsigned)(unsigned short)f2bf(v1.w) << 16) | (unsigned short)f2bf(v1.z);
            *reinterpret_cast<uint2*>(&sband[base + swz_col(cq + 4, r)]) = u;
            u.x = ((unsigned)(unsigned short)f2bf(v2.y) << 16) | (unsigned short)f2bf(v2.x);
            u.y = ((unsigned)(unsigned short)f2bf(v2.w) << 16) | (unsigned short)f2bf(v2.z);
            *reinterpret_cast<uint2*>(&sband[base + swz_col(cq + 8, r)]) = u;
            u.x = ((unsigned)(unsigned short)f2bf(v3.y) << 16) | (unsigned short)f2bf(v3.x);
            u.y = ((unsigned)(unsigned short)f2bf(v3.w) << 16) | (unsigned short)f2bf(v3.z);
            *reinterpret_cast<uint2*>(&sband[base + swz_col(cq + 12, r)]) = u;
        }
    }
    __syncthreads();

    const int col = lane & 15;
    const int kb  = (lane >> 4) * 8;
    const int g   = lane >> 4;

    // ---- weights: lane-dependent only -> hoist once per wave (L1-hot)
    bf16x8 afrag[4][5];
#pragma unroll
    for (int ct = 0; ct < 4; ++ct)
#pragma unroll
        for (int ks = 0; ks < 5; ++ks)
            afrag[ct][ks] = *reinterpret_cast<const bf16x8*>(
                wt + (ct * 16 + col) * KPAD + ks * 32 + kb);

    // ---- per-lane BN partial accumulators (ch = ct*16 + g*4 + r)
    float ssum[4][4], sqsum[4][4];
#pragma unroll
    for (int ct = 0; ct < 4; ++ct)
#pragma unroll
        for (int r = 0; r < 4; ++r) { ssum[ct][r] = 0.f; sqsum[ct][r] = 0.f; }

    // ---- 7 tile-pairs per wave: iA = wv+16pp, iB = iA+8
    for (int pp = 0; pp < 7; ++pp) {
        const int iA = wv + 16 * pp;
        const int iB = iA + 8;

        const unsigned short* opA = tbl + (size_t)(jt * L + iA) * TILE_U16 + lane * 8;
        const unsigned short* opB = tbl + (size_t)(jt * L + iB) * TILE_U16 + lane * 8;
        ushort8 ovA[5], ovB[5];
#pragma unroll
        for (int ks = 0; ks < 5; ++ks)
            ovA[ks] = *reinterpret_cast<const ushort8*>(opA + ks * 512);
#pragma unroll
        for (int ks = 0; ks < 5; ++ks)
            ovB[ks] = *reinterpret_cast<const ushort8*>(opB + ks * 512);

        // 80 independent LDS gathers into disjoint register sets
        bf16x8 bfA[5], bfB[5];
#pragma unroll
        for (int ks = 0; ks < 5; ++ks)
#pragma unroll
            for (int e = 0; e < 8; ++e)
                bfA[ks][e] = (short)sband[ovA[ks][e]];
#pragma unroll
        for (int ks = 0; ks < 5; ++ks)
#pragma unroll
            for (int e = 0; e < 8; ++e)
                bfB[ks][e] = (short)sband[ovB[ks][e]];

        f32x4 accA[4], accB[4];
#pragma unroll
        for (int ct = 0; ct < 4; ++ct) {
            accA[ct] = (f32x4){0.f, 0.f, 0.f, 0.f};
            accB[ct] = (f32x4){0.f, 0.f, 0.f, 0.f};
        }

        __builtin_amdgcn_s_setprio(1);
#pragma unroll
        for (int ks = 0; ks < 5; ++ks)
#pragma unroll
            for (int ct = 0; ct < 4; ++ct)
                accA[ct] = __builtin_amdgcn_mfma_f32_16x16x32_bf16(
                    afrag[ct][ks], bfA[ks], accA[ct], 0, 0, 0);
        __builtin_amdgcn_s_setprio(0);

        if (BF16OUT) {
            const size_t cbaseA = ((size_t)((b * NJT + jt) * L + iA)) * PBLK;
#pragma unroll
            for (int ct = 0; ct < 4; ++ct) {
                us4 pk;
#pragma unroll
                for (int r = 0; r < 4; ++r) {
                    const float v = accA[ct][r];
                    pk[r] = (unsigned short)f2bf(v);
                    ssum[ct][r]  += v;
                    sqsum[ct][r] += v * v;
                }
                *reinterpret_cast<us4*>(
                    out_bf16 + cbaseA + ((ct * 4 + g) * 16 + col) * 4) = pk;
            }
        } else {
            const size_t obaseA = (size_t)b * COUT * PLANE + iA * L + jt * W + col;
#pragma unroll
            for (int ct = 0; ct < 4; ++ct)
#pragma unroll
                for (int r = 0; r < 4; ++r) {
                    const float v = accA[ct][r];
                    out_f32[obaseA + (size_t)(ct * 16 + g * 4 + r) * PLANE] = v;
                    ssum[ct][r]  += v;
                    sqsum[ct][r] += v * v;
                }
        }

        __builtin_amdgcn_s_setprio(1);
#pragma unroll
        for (int ks = 0; ks < 5; ++ks)
#pragma unroll
            for (int ct = 0; ct < 4; ++ct)
                accB[ct] = __builtin_amdgcn_mfma_f32_16x16x32_bf16(
                    afrag[ct][ks], bfB[ks], accB[ct], 0, 0, 0);
        __builtin_amdgcn_s_setprio(0);

        if (BF16OUT) {
            const size_t cbaseB = ((size_t)((b * NJT + jt) * L + iB)) * PBLK;
#pragma unroll
            for (int ct = 0; ct < 4; ++ct) {
                us4 pk;
#pragma unroll
                for (int r = 0; r < 4; ++r) {
                    const float v = accB[ct][r];
                    pk[r] = (unsigned short)f2bf(v);
                    ssum[ct][r]  += v;
                    sqsum[ct][r] += v * v;
                }
                *reinterpret_cast<us4*>(
                    out_bf16 + cbaseB + ((ct * 4 + g) * 16 + col) * 4) = pk;
            }
        } else {
            const size_t obaseB = (size_t)b * COUT * PLANE + iB * L + jt * W + col;
#pragma unroll
            for (int ct = 0; ct < 4; ++ct)
#pragma unroll
                for (int r = 0; r < 4; ++r) {
                    const float v = accB[ct][r];
                    out_f32[obaseB + (size_t)(ct * 16 + g * 4 + r) * PLANE] = v;
                    ssum[ct][r]  += v;
                    sqsum[ct][r] += v * v;
                }
        }
    }

    // ---- fold per-lane stats: reduce over the 16 cols of each group
#pragma unroll
    for (int ct = 0; ct < 4; ++ct)
#pragma unroll
        for (int r = 0; r < 4; ++r) {
#pragma unroll
            for (int m = 1; m < 16; m <<= 1) {
                ssum[ct][r]  += __shfl_xor(ssum[ct][r],  m);
                sqsum[ct][r] += __shfl_xor(sqsum[ct][r], m);
            }
        }
    if (col == 0) {
#pragma unroll
        for (int ct = 0; ct < 4; ++ct)
#pragma unroll
            for (int r = 0; r < 4; ++r) {
                const int ch = ct * 16 + g * 4 + r;
                atomicAdd(&ps[ch], ssum[ct][r]);
                atomicAdd(&ps[COUT + ch], sqsum[ct][r]);
            }
    }
    __syncthreads();
    if (tid < 2 * COUT) partial[(size_t)blockIdx.x * (2 * COUT) + tid] = ps[tid];
}

// ---------------------------------------------------------------------------
// Fold: per-channel scale/shift from block partials.
// ---------------------------------------------------------------------------
__global__ __launch_bounds__(256) void fold_stats(
    const float* __restrict__ partial, const float* __restrict__ gamma,
    const float* __restrict__ beta, float* __restrict__ wsf)
{
    const int o = blockIdx.x;                 // 64 blocks
    float s = 0.f, sq = 0.f;
    for (int t = threadIdx.x; t < NB; t += 256) {
        s  += partial[(size_t)t * (2 * COUT) + o];
        sq += partial[(size_t)t * (2 * COUT) + COUT + o];
    }
#pragma unroll
    for (int m = 1; m < 64; m <<= 1) {
        s  += __shfl_xor(s, m);
        sq += __shfl_xor(sq, m);
    }
    __shared__ float ls[4], lsq[4];
    const int wid = threadIdx.x >> 6;
    if ((threadIdx.x & 63) == 0) { ls[wid] = s; lsq[wid] = sq; }
    __syncthreads();
    if (threadIdx.x == 0) {
        s  = ls[0] + ls[1] + ls[2] + ls[3];
        sq = lsq[0] + lsq[1] + lsq[2] + lsq[3];
        const float n = (float)NPOS;
        const float mean = s / n;
        float var = sq / n - mean * mean;
        var = fmaxf(var, 0.f);
        const float sc = gamma[o] * rsqrtf(var + EPS);
        wsf[o] = sc;
        wsf[COUT + o] = beta[o] - mean * sc;
    }
}

// ---------------------------------------------------------------------------
// Norm + ReLU from the PACKED cbf layout [b][jt][i][ct][g][col][r].
// Thread reads ushort8 (col pair x 4 r), writes 4x float2 to canonical out.
// ---------------------------------------------------------------------------
__global__ __launch_bounds__(256) void norm_relu_pk(
    const unsigned short* __restrict__ in, float* __restrict__ out,
    const float* __restrict__ wsf)
{
    const int idx = blockIdx.x * 256 + threadIdx.x;   // < NTOT/8 (exact grid)
    const int e   = idx * 8;
    const int blk = e >> 10;                  // (b*NJT + jt)*L + i
    const int sub = e & 1023;
    const int ctg  = sub >> 6;                // ct*4 + g
    const int col0 = (sub >> 2) & 15;         // even
    const int i  = blk % L;
    const int bj = blk / L;
    const int jt = bj % NJT;
    const int b  = bj / NJT;
    const int chb = (ctg >> 2) * 16 + (ctg & 3) * 4;

    const ushort8 u = *reinterpret_cast<const ushort8*>(in + e);
    const size_t obase = ((size_t)(b * COUT + chb)) * PLANE
                       + (size_t)i * L + jt * W + col0;
#pragma unroll
    for (int r = 0; r < 4; ++r) {
        const float sc = wsf[chb + r];
        const float sh = wsf[COUT + chb + r];
        float2 w;
        w.x = fmaxf(fmaf(bf2f(u[r]),     sc, sh), 0.f);
        w.y = fmaxf(fmaf(bf2f(u[4 + r]), sc, sh), 0.f);
        *reinterpret_cast<float2*>(out + obase + (size_t)r * PLANE) = w;
    }
}

// fp32 in-place fallback (canonical layout)
__global__ __launch_bounds__(256) void norm_relu(
    float4* __restrict__ out, const float* __restrict__ wsf)
{
    const int idx = blockIdx.x * 256 + threadIdx.x;   // < NTOT/4
    const int o = (idx / (PLANE / 4)) & (COUT - 1);
    const float sc = wsf[o];
    const float sh = wsf[COUT + o];
    float4 v = out[idx];
    v.x = fmaxf(fmaf(v.x, sc, sh), 0.f);
    v.y = fmaxf(fmaf(v.y, sc, sh), 0.f);
    v.z = fmaxf(fmaf(v.z, sc, sh), 0.f);
    v.w = fmaxf(fmaf(v.w, sc, sh), 0.f);
    out[idx] = v;
}

// ---------------------------------------------------------------------------
extern "C" void kernel_launch(void* const* d_in, const int* in_sizes, int n_in,
                              void* d_out, int out_size, void* d_ws, size_t ws_size,
                              hipStream_t stream)
{
    const float* x      = (const float*)d_in[0];
    const float* conv_w = (const float*)d_in[1];
    const float* gamma  = (const float*)d_in[2];
    const float* beta   = (const float*)d_in[3];
    const int*   locs_i = (const int*)d_in[4];
    const int*   locs_j = (const int*)d_in[5];
    float* out = (float*)d_out;

    float* wsf   = (float*)d_ws;                                    // 512 B
    int* row_lo  = (int*)((char*)d_ws + 512);                       // 28 B
    int* row_hi  = (int*)((char*)d_ws + 768);                       // 28 B
    unsigned short* wt = (unsigned short*)((char*)d_ws + 2048);     // 20480 B
    float* partial = (float*)((char*)d_ws + 32768);                 // 114688 B
    unsigned short* tbl =
        (unsigned short*)((char*)d_ws + (1u << 20));                // 4.01 MB
    unsigned short* cbf =
        (unsigned short*)((char*)d_ws + (6u << 20));                // 51.4 MB

    const bool use_bf16 = ws_size >= (size_t)(6u << 20) + (size_t)NTOT * 2;

    hipMemsetAsync(row_lo, 0x7F, NJT * sizeof(int), stream);        // +big
    hipMemsetAsync(row_hi, 0x80, NJT * sizeof(int), stream);        // -big

    prep_wt_minmax<<<WBLK + MMBLK, 256, 0, stream>>>(
        conv_w, wt, locs_i, row_lo, row_hi);
    prep_ldsoff<<<(NTBL + 255) / 256, 256, 0, stream>>>(
        locs_i, locs_j, row_lo, tbl);
    if (use_bf16) {
        foveal_conv_mfma<true><<<NB, CONVTH, 0, stream>>>(
            x, wt, tbl, row_lo, row_hi, out, cbf, partial);
        fold_stats<<<COUT, 256, 0, stream>>>(partial, gamma, beta, wsf);
        norm_relu_pk<<<NTOT / 8 / 256, 256, 0, stream>>>(cbf, out, wsf);
    } else {
        foveal_conv_mfma<false><<<NB, CONVTH, 0, stream>>>(
            x, wt, tbl, row_lo, row_hi, out, cbf, partial);
        fold_stats<<<COUT, 256, 0, stream>>>(partial, gamma, beta, wsf);
        norm_relu<<<NTOT / 4 / 256, 256, 0, stream>>>((float4*)out, wsf);
    }
}